// Round 13
// baseline (572.928 us; speedup 1.0000x reference)
//
#include <hip/hip_runtime.h>
#include <hip/hip_bf16.h>
#include <hip/hip_fp16.h>

#define NN 50000
#define NP 50176              // NN padded to multiple of 256
#define EE 800000
#define ET (EE + NN)          // 850000 edges incl self-loops

typedef __attribute__((ext_vector_type(4))) float f32x4;

static __device__ __forceinline__ float bf2f(__hip_bfloat16 x) { return __bfloat162float(x); }
static __device__ __forceinline__ ushort f2bu(float f) {
    union { __hip_bfloat16 b; ushort u; } c;
    c.b = __float2bfloat16(f);
    return c.u;
}
// fp8 e4m3 HW conversion (gfx950)
static __device__ __forceinline__ unsigned char f2fp8(float v) {
    int p = __builtin_amdgcn_cvt_pk_fp8_f32(v, v, 0, false);
    return (unsigned char)(p & 0xff);
}
static __device__ __forceinline__ unsigned pk4fp8(float a, float b, float c, float d) {
    unsigned lo = (unsigned)__builtin_amdgcn_cvt_pk_fp8_f32(a, b, 0, false) & 0xffffu;
    unsigned hi = (unsigned)__builtin_amdgcn_cvt_pk_fp8_f32(c, d, 0, false) & 0xffffu;
    return lo | (hi << 16);
}
// decode 4 packed fp8 bytes, accumulate w*val into acc[0..3]
static __device__ __forceinline__ void fp8acc4(unsigned v, float w, float* acc) {
#if __has_builtin(__builtin_amdgcn_cvt_pk_f32_fp8)
    auto f01 = __builtin_amdgcn_cvt_pk_f32_fp8((int)v, false);
    auto f23 = __builtin_amdgcn_cvt_pk_f32_fp8((int)v, true);
    acc[0] += w * f01[0];
    acc[1] += w * f01[1];
    acc[2] += w * f23[0];
    acc[3] += w * f23[1];
#else
    acc[0] += w * __builtin_amdgcn_cvt_f32_fp8(v, 0);
    acc[1] += w * __builtin_amdgcn_cvt_f32_fp8(v, 1);
    acc[2] += w * __builtin_amdgcn_cvt_f32_fp8(v, 2);
    acc[3] += w * __builtin_amdgcn_cvt_f32_fp8(v, 3);
#endif
}
// async global->LDS DMA, 16B/lane; lds dest wave-uniform base + lane*16
static __device__ __forceinline__ void gl2lds(const unsigned char* g, unsigned char* l) {
    __builtin_amdgcn_global_load_lds(
        (const __attribute__((address_space(1))) void*)g,
        (__attribute__((address_space(3))) void*)l,
        16, 0, 0);
}

// ---------------------------------------------------------------- fused prep + CSR count
#define PA1 (256 * 448)
#define PA2 (448 * 448)
#define PA3 (448 * 32)
#define PXQ (NN * 64)   // x float4-quads
#define PTOT (PA1 + PA2 + PA3 + PXQ)
#define PBLK ((PTOT + 255) / 256)
#define CBLK ((ET + 255) / 256)

__global__ void gat_prepcnt_kernel(const float* __restrict__ W1, const float* __restrict__ W2,
                                   const float* __restrict__ W3, const float* __restrict__ x,
                                   unsigned char* __restrict__ Wt1, unsigned char* __restrict__ Wt2,
                                   unsigned char* __restrict__ Wt3, unsigned char* __restrict__ xb,
                                   const int* __restrict__ ei, int* __restrict__ cnt) {
    int b = blockIdx.x;
    if (b >= PBLK) {
        int i = (b - PBLK) * 256 + threadIdx.x;
        if (i < ET) {
            int dst = (i < EE) ? ei[EE + i] : (i - EE);
            atomicAdd(&cnt[dst], 1);
        }
        return;
    }
    int i = b * 256 + threadIdx.x;
    if (i < PA1) {
        int k = i / 448, n = i - k * 448;
        Wt1[(size_t)n * 256 + k] = f2fp8(W1[i]);
        return;
    }
    i -= PA1;
    if (i < PA2) {
        int k = i / 448, n = i - k * 448;
        Wt2[(size_t)n * 448 + k] = f2fp8(W2[i]);
        return;
    }
    i -= PA2;
    if (i < PA3) {
        int k = i / 32, n = i - k * 32;
        Wt3[(size_t)n * 448 + k] = f2fp8(W3[i]);
        return;
    }
    i -= PA3;
    if (i < PXQ) {
        float4 f = ((const float4*)x)[i];
        ((unsigned*)xb)[i] = pk4fp8(f.x, f.y, f.z, f.w);
    }
}

// ---------------------------------------------------------------- single-kernel scan (1 block x 1024)
__global__ void gat_scanall_kernel(const int* __restrict__ cnt, int* __restrict__ row_ptr) {
    __shared__ int sm[1024];
    const int C = 49;   // 49*1024 = 50176 >= NN
    int t = threadIdx.x;
    int base = t * C;
    int s = 0;
    for (int i = 0; i < C; i++) {
        int idx = base + i;
        if (idx < NN) s += cnt[idx];
    }
    sm[t] = s;
    __syncthreads();
    for (int o = 1; o < 1024; o <<= 1) {
        int v = (t >= o) ? sm[t - o] : 0;
        __syncthreads();
        sm[t] += v;
        __syncthreads();
    }
    int run = (t > 0) ? sm[t - 1] : 0;
    for (int i = 0; i < C; i++) {
        int idx = base + i;
        if (idx < NN) {
            run += cnt[idx];
            row_ptr[idx + 1] = run;
        }
    }
    if (t == 0) row_ptr[0] = 0;
}

__global__ void gat_fill_kernel(const int* __restrict__ ei, const int* __restrict__ row_ptr,
                                int* __restrict__ fillc, int* __restrict__ colA) {
    int i = blockIdx.x * blockDim.x + threadIdx.x;
    if (i >= ET) return;
    int s, d;
    if (i < EE) { s = ei[i]; d = ei[EE + i]; }
    else        { s = d = i - EE; }
    int pos = row_ptr[d] + atomicAdd(&fillc[d], 1);
    colA[pos] = s;
}

// ---------------------------------------------------------------- GEMM core (fp8 A & W, fp8 MFMA, DMA staging, dbuf)
// C[M,N] = A[M,K] * W[K,N]; W pre-transposed fp8 Wt[N][K] (rows padded >= n0+64). A padded to NP rows.
// RF = 16-row frags/wave (BM = RF*64). GBK=64 (two K=32 MFMA steps per tile).
// DOA=1: fuse 64-ch alpha (head=blockIdx.y). DOA=2: 32-ch alpha. OM=0: C bf16; OM=1: C fp8.
#define GBN 64
#define GBK 64

template <int RF, int DOA, int OM>
__global__ __launch_bounds__(256) void gat_gemm_kernel(
    const unsigned char* __restrict__ A, const unsigned char* __restrict__ Wt,
    void* __restrict__ Cv,
    const float* __restrict__ Asrc, const float* __restrict__ Adst,
    float* __restrict__ as8, float* __restrict__ ad8,
    int M, int K, int N) {
    constexpr int GBM = RF * 64;
    __shared__ __align__(16) unsigned char As[2][GBM * GBK];
    __shared__ __align__(16) unsigned char Bs[2][GBN * GBK];
    int tid = threadIdx.x;
    int wave = tid >> 6, lane = tid & 63;
    int lrow = lane & 15, lq = lane >> 4;
    int m0 = blockIdx.x * GBM, n0 = blockIdx.y * GBN;
    int srow = lane >> 2, schunk = (lane & 3) * 16;     // 4 lanes per 64B row
    f32x4 acc[RF][4] = {};

    int KT = K / GBK;
    {
#pragma unroll
        for (int q = 0; q < RF; q++) {
            const unsigned char* gp = A + (size_t)(m0 + wave * RF * 16 + q * 16 + srow) * K + schunk;
            gl2lds(gp, &As[0][(wave * RF * 16 + q * 16) * GBK]);
        }
        const unsigned char* gb = Wt + (size_t)(n0 + wave * 16 + srow) * K + schunk;
        gl2lds(gb, &Bs[0][wave * 16 * GBK]);
    }
    for (int kt = 0; kt < KT; kt++) {
        __syncthreads();
        if (kt + 1 < KT) {
            int nb = (kt + 1) & 1, k0 = (kt + 1) * GBK;
#pragma unroll
            for (int q = 0; q < RF; q++) {
                const unsigned char* gp = A + (size_t)(m0 + wave * RF * 16 + q * 16 + srow) * K + k0 + schunk;
                gl2lds(gp, &As[nb][(wave * RF * 16 + q * 16) * GBK]);
            }
            const unsigned char* gb = Wt + (size_t)(n0 + wave * 16 + srow) * K + k0 + schunk;
            gl2lds(gb, &Bs[nb][wave * 16 * GBK]);
        }
        int b = kt & 1;
#pragma unroll
        for (int s = 0; s < 2; s++) {
            long af[RF];
#pragma unroll
            for (int rf = 0; rf < RF; rf++)
                af[rf] = *(const long*)&As[b][(wave * RF * 16 + rf * 16 + lrow) * GBK + s * 32 + lq * 8];
#pragma unroll
            for (int ng = 0; ng < 4; ng++) {
                long bf = *(const long*)&Bs[b][(ng * 16 + lrow) * GBK + s * 32 + lq * 8];
#pragma unroll
                for (int rf = 0; rf < RF; rf++)
                    acc[rf][ng] = __builtin_amdgcn_mfma_f32_16x16x32_fp8_fp8(af[rf], bf, acc[rf][ng], 0, 0, 0);
            }
        }
    }
    // epilogue: C/D layout col=lane&15 (within ng group), row=lq*4+r
#pragma unroll
    for (int rf = 0; rf < RF; rf++)
#pragma unroll
        for (int ng = 0; ng < 4; ng++)
#pragma unroll
            for (int r = 0; r < 4; r++) {
                int row = m0 + wave * RF * 16 + rf * 16 + lq * 4 + r;
                int colI = n0 + ng * 16 + lrow;
                if (row < M && colI < N) {
                    if constexpr (OM == 0)
                        ((__hip_bfloat16*)Cv)[(size_t)row * N + colI] = __float2bfloat16(acc[rf][ng][r]);
                    else
                        ((unsigned char*)Cv)[(size_t)row * N + colI] = f2fp8(acc[rf][ng][r]);
                }
            }
    if constexpr (DOA == 1) {
        int head = blockIdx.y;
        float as_l[4], ad_l[4];
#pragma unroll
        for (int ng = 0; ng < 4; ng++) {
            as_l[ng] = Asrc[head * 64 + ng * 16 + lrow];
            ad_l[ng] = Adst[head * 64 + ng * 16 + lrow];
        }
#pragma unroll
        for (int rf = 0; rf < RF; rf++)
#pragma unroll
            for (int r = 0; r < 4; r++) {
                float ps = 0.f, pd = 0.f;
#pragma unroll
                for (int ng = 0; ng < 4; ng++) {
                    ps += acc[rf][ng][r] * as_l[ng];
                    pd += acc[rf][ng][r] * ad_l[ng];
                }
#pragma unroll
                for (int o = 1; o < 16; o <<= 1) {
                    ps += __shfl_xor(ps, o);
                    pd += __shfl_xor(pd, o);
                }
                int row = m0 + wave * RF * 16 + rf * 16 + lq * 4 + r;
                if (lrow == 0 && row < M) {
                    as8[(size_t)row * 8 + head] = ps;
                    ad8[(size_t)row * 8 + head] = pd;
                }
            }
    } else if constexpr (DOA == 2) {
        float as_l[2], ad_l[2];
#pragma unroll
        for (int ng = 0; ng < 2; ng++) {
            as_l[ng] = Asrc[ng * 16 + lrow];
            ad_l[ng] = Adst[ng * 16 + lrow];
        }
#pragma unroll
        for (int rf = 0; rf < RF; rf++)
#pragma unroll
            for (int r = 0; r < 4; r++) {
                float ps = acc[rf][0][r] * as_l[0] + acc[rf][1][r] * as_l[1];
                float pd = acc[rf][0][r] * ad_l[0] + acc[rf][1][r] * ad_l[1];
#pragma unroll
                for (int o = 1; o < 16; o <<= 1) {
                    ps += __shfl_xor(ps, o);
                    pd += __shfl_xor(pd, o);
                }
                int row = m0 + wave * RF * 16 + rf * 16 + lq * 4 + r;
                if (lrow == 0 && row < M) {
                    as8[(size_t)row * 8] = ps;
                    ad8[(size_t)row * 8] = pd;
                }
            }
    }
}

// ---------------------------------------------------------------- Phase C: wave-per-dst, fp8 gather, fp8 act out
// lane l<56 owns head l>>3, channels 8l..8l+7 (8B/lane fp8 gather + 8B/lane fp8 store)
__global__ void gat_aggC7_kernel(const int* __restrict__ rp, const int* __restrict__ colA,
                                 const float* __restrict__ as8, const float* __restrict__ ad8,
                                 const unsigned char* __restrict__ h8,
                                 const float* __restrict__ bias,
                                 unsigned char* __restrict__ outp) {
    int d = blockIdx.x * 4 + (threadIdx.x >> 6);
    if (d >= NN) return;
    int lane = threadIdx.x & 63;
    if (lane >= 56) return;
    int hh = lane >> 3;
    float adh = ad8[(size_t)d * 8 + hh];
    int s0 = rp[d], s1 = rp[d + 1];
    float acc[8] = {0.f, 0.f, 0.f, 0.f, 0.f, 0.f, 0.f, 0.f};
    float den = 0.f;
    int j = s0;
    for (; j + 4 <= s1; j += 4) {
        int sA = colA[j], sB = colA[j + 1], sC = colA[j + 2], sD = colA[j + 3];
        float eA = as8[(size_t)sA * 8 + hh] + adh;
        float eB = as8[(size_t)sB * 8 + hh] + adh;
        float eC = as8[(size_t)sC * 8 + hh] + adh;
        float eD = as8[(size_t)sD * 8 + hh] + adh;
        uint2 hA = *(const uint2*)(h8 + (size_t)sA * 448 + lane * 8);
        uint2 hB = *(const uint2*)(h8 + (size_t)sB * 448 + lane * 8);
        uint2 hC = *(const uint2*)(h8 + (size_t)sC * 448 + lane * 8);
        uint2 hD = *(const uint2*)(h8 + (size_t)sD * 448 + lane * 8);
        eA = (eA > 0.f) ? eA : 0.2f * eA;
        eB = (eB > 0.f) ? eB : 0.2f * eB;
        eC = (eC > 0.f) ? eC : 0.2f * eC;
        eD = (eD > 0.f) ? eD : 0.2f * eD;
        float wA = __expf(eA), wB = __expf(eB);
        float wC = __expf(eC), wD = __expf(eD);
        den += (wA + wB) + (wC + wD);
        fp8acc4(hA.x, wA, &acc[0]); fp8acc4(hA.y, wA, &acc[4]);
        fp8acc4(hB.x, wB, &acc[0]); fp8acc4(hB.y, wB, &acc[4]);
        fp8acc4(hC.x, wC, &acc[0]); fp8acc4(hC.y, wC, &acc[4]);
        fp8acc4(hD.x, wD, &acc[0]); fp8acc4(hD.y, wD, &acc[4]);
    }
    for (; j < s1; j++) {
        int s = colA[j];
        float e = as8[(size_t)s * 8 + hh] + adh;
        e = (e > 0.f) ? e : 0.2f * e;
        float w = __expf(e);
        uint2 hv = *(const uint2*)(h8 + (size_t)s * 448 + lane * 8);
        den += w;
        fp8acc4(hv.x, w, &acc[0]);
        fp8acc4(hv.y, w, &acc[4]);
    }
    float inv = 1.f / (den + 1e-16f);
    const float4* bp = (const float4*)(bias + lane * 8);
    float4 bb0 = bp[0], bb1 = bp[1];
    float bv[8] = {bb0.x, bb0.y, bb0.z, bb0.w, bb1.x, bb1.y, bb1.z, bb1.w};
    float o[8];
#pragma unroll
    for (int k = 0; k < 8; k++) o[k] = fmaxf(acc[k] * inv + bv[k], 0.f);
    uint2 packed;
    packed.x = pk4fp8(o[0], o[1], o[2], o[3]);
    packed.y = pk4fp8(o[4], o[5], o[6], o[7]);
    *(uint2*)(outp + (size_t)d * 448 + lane * 8) = packed;
}

// ---------------------------------------------------------------- Phase C final: 2 dsts/wave, 32 ch (bf16 h3), log_softmax
__global__ void gat_aggCF_kernel(const int* __restrict__ rp, const int* __restrict__ colA,
                                 const float* __restrict__ as8, const float* __restrict__ ad8,
                                 const __hip_bfloat16* __restrict__ h,
                                 const float* __restrict__ bias,
                                 float* __restrict__ outp) {
    int wid = blockIdx.x * 4 + (threadIdx.x >> 6);
    int lane = threadIdx.x & 63;
    int half = lane >> 5, c = lane & 31;
    int dreal = wid * 2 + half;
    bool valid = dreal < NN;
    int d = valid ? dreal : (NN - 1);
    float adh = ad8[(size_t)d * 8];
    int s0 = rp[d], s1 = rp[d + 1];
    float acc = 0.f, den = 0.f;
    int j = s0;
    for (; j + 2 <= s1; j += 2) {
        int sA = colA[j], sB = colA[j + 1];
        float eA = as8[(size_t)sA * 8] + adh;
        float eB = as8[(size_t)sB * 8] + adh;
        float vA = bf2f(h[(size_t)sA * 32 + c]);
        float vB = bf2f(h[(size_t)sB * 32 + c]);
        eA = (eA > 0.f) ? eA : 0.2f * eA;
        eB = (eB > 0.f) ? eB : 0.2f * eB;
        float wA = __expf(eA), wB = __expf(eB);
        den += wA + wB;
        acc += wA * vA + wB * vB;
    }
    for (; j < s1; j++) {
        int s = colA[j];
        float e = as8[(size_t)s * 8] + adh;
        e = (e > 0.f) ? e : 0.2f * e;
        float w = __expf(e);
        den += w;
        acc += w * bf2f(h[(size_t)s * 32 + c]);
    }
    float o = acc / (den + 1e-16f) + bias[c];
    float t = o;
#pragma unroll
    for (int off = 16; off > 0; off >>= 1) t = fmaxf(t, __shfl_xor(t, off));
    float ex = __expf(o - t);
#pragma unroll
    for (int off = 16; off > 0; off >>= 1) ex += __shfl_xor(ex, off);
    float res = o - t - __logf(ex);
    if (valid) outp[(size_t)d * 32 + c] = res;
}

// ---------------------------------------------------------------- launch
extern "C" void kernel_launch(void* const* d_in, const int* in_sizes, int n_in,
                              void* d_out, int out_size, void* d_ws, size_t ws_size,
                              hipStream_t stream) {
    const float* x   = (const float*)d_in[0];
    const int*   ei  = (const int*)d_in[1];
    const float* W1  = (const float*)d_in[2];
    const float* a1s = (const float*)d_in[3];
    const float* a1d = (const float*)d_in[4];
    const float* b1  = (const float*)d_in[5];
    const float* W2  = (const float*)d_in[6];
    const float* a2s = (const float*)d_in[7];
    const float* a2d = (const float*)d_in[8];
    const float* b2  = (const float*)d_in[9];
    const float* W3  = (const float*)d_in[10];
    const float* a3s = (const float*)d_in[11];
    const float* a3d = (const float*)d_in[12];
    const float* b3  = (const float*)d_in[13];
    float* out = (float*)d_out;

    // workspace layout (~70 MB); all GEMM inputs fp8, padded to NP rows
    char* w = (char*)d_ws;
    unsigned char* hbuf8 = (unsigned char*)w;                  // NP*448 fp8 (22.5 MB); layer-3 reuses as bf16 NP*32
    __hip_bfloat16* hbuf3 = (__hip_bfloat16*)w;
    unsigned char* xb  = (unsigned char*)(w + (size_t)NP * 448);     // NP*256 fp8 (12.8 MB)
    unsigned char* act = xb + (size_t)NP * 256;                // NP*448 fp8 (22.5 MB)
    float* as8 = (float*)(act + (size_t)NP * 448);             // N*8 f32
    float* ad8 = as8 + (size_t)NN * 8;                         // N*8 f32
    int* cnt     = (int*)(ad8 + (size_t)NN * 8);               // N
    int* fillc   = cnt + NN;                                   // N
    int* row_ptr = fillc + NN;                                 // N+4 (padded)
    int* colA    = row_ptr + (NN + 4);                         // ET
    char* pw = (char*)(colA + ET);
    pw = (char*)(((uintptr_t)pw + 15) & ~(uintptr_t)15);
    unsigned char* Wt1 = (unsigned char*)pw;                   // 448*256 fp8
    unsigned char* Wt2 = Wt1 + 448 * 256;                      // 448*448 fp8
    unsigned char* Wt3 = Wt2 + 448 * 448;                      // 64*448 fp8 (rows 32..63 poison, never stored)

    hipMemsetAsync(cnt, 0, 2 * (size_t)NN * sizeof(int), stream);  // cnt + fillc

    // fused prep (Wt x3 fp8 + x->fp8) + CSR count
    gat_prepcnt_kernel<<<PBLK + CBLK, 256, 0, stream>>>(W1, W2, W3, x, Wt1, Wt2, Wt3, xb, ei, cnt);
    gat_scanall_kernel<<<1, 1024, 0, stream>>>(cnt, row_ptr);
    gat_fill_kernel<<<CBLK, 256, 0, stream>>>(ei, row_ptr, fillc, colA);

    dim3 gemmBlk(256);
    int mtiles = NP / 256;              // 196 (RF=4)
    int mtiles1 = NP / 64;              // 784 (RF=1, layer 3)
    int aggBlocks = (NN + 3) / 4;       // 12500

    // --- layer 1 (fp8 GEMM, alpha fused; h written fp8)
    gat_gemm_kernel<4, 1, 1><<<dim3(mtiles, 7), gemmBlk, 0, stream>>>(
        xb, Wt1, hbuf8, a1s, a1d, as8, ad8, NN, 256, 448);
    gat_aggC7_kernel<<<aggBlocks, 256, 0, stream>>>(row_ptr, colA, as8, ad8, hbuf8, b1, act);

    // --- layer 2
    gat_gemm_kernel<4, 1, 1><<<dim3(mtiles, 7), gemmBlk, 0, stream>>>(
        act, Wt2, hbuf8, a2s, a2d, as8, ad8, NN, 448, 448);
    gat_aggC7_kernel<<<aggBlocks, 256, 0, stream>>>(row_ptr, colA, as8, ad8, hbuf8, b2, act);

    // --- layer 3 (1 head, 32 ch, alpha fused, bf16 h3, RF=1, log_softmax, fp32 out)
    gat_gemm_kernel<1, 2, 0><<<dim3(mtiles1, 1), gemmBlk, 0, stream>>>(
        act, Wt3, hbuf3, a3s, a3d, as8, ad8, NN, 448, 32);
    int fBlocks = (NN + 7) / 8;  // 8 dsts per block (2 per wave)
    gat_aggCF_kernel<<<fBlocks, 256, 0, stream>>>(row_ptr, colA, as8, ad8, hbuf3, b3, out);
}

// Round 14
// 494.074 us; speedup vs baseline: 1.1596x; 1.1596x over previous
//
#include <hip/hip_runtime.h>
#include <hip/hip_bf16.h>
#include <hip/hip_fp16.h>

#define NN 50000
#define NP 50176              // NN padded to multiple of 256
#define EE 800000
#define ET (EE + NN)          // 850000 edges incl self-loops
#define NB_SCAN ((NN + 255) / 256)   // 196

typedef __attribute__((ext_vector_type(4))) float f32x4;

static __device__ __forceinline__ float bf2f(__hip_bfloat16 x) { return __bfloat162float(x); }
static __device__ __forceinline__ ushort f2bu(float f) {
    union { __hip_bfloat16 b; ushort u; } c;
    c.b = __float2bfloat16(f);
    return c.u;
}
// fp8 e4m3 HW conversion (gfx950)
static __device__ __forceinline__ unsigned char f2fp8(float v) {
    int p = __builtin_amdgcn_cvt_pk_fp8_f32(v, v, 0, false);
    return (unsigned char)(p & 0xff);
}
static __device__ __forceinline__ unsigned pk4fp8(float a, float b, float c, float d) {
    unsigned lo = (unsigned)__builtin_amdgcn_cvt_pk_fp8_f32(a, b, 0, false) & 0xffffu;
    unsigned hi = (unsigned)__builtin_amdgcn_cvt_pk_fp8_f32(c, d, 0, false) & 0xffffu;
    return lo | (hi << 16);
}
// decode 4 packed fp8 bytes, accumulate w*val into acc[0..3]
static __device__ __forceinline__ void fp8acc4(unsigned v, float w, float* acc) {
#if __has_builtin(__builtin_amdgcn_cvt_pk_f32_fp8)
    auto f01 = __builtin_amdgcn_cvt_pk_f32_fp8((int)v, false);
    auto f23 = __builtin_amdgcn_cvt_pk_f32_fp8((int)v, true);
    acc[0] += w * f01[0];
    acc[1] += w * f01[1];
    acc[2] += w * f23[0];
    acc[3] += w * f23[1];
#else
    acc[0] += w * __builtin_amdgcn_cvt_f32_fp8(v, 0);
    acc[1] += w * __builtin_amdgcn_cvt_f32_fp8(v, 1);
    acc[2] += w * __builtin_amdgcn_cvt_f32_fp8(v, 2);
    acc[3] += w * __builtin_amdgcn_cvt_f32_fp8(v, 3);
#endif
}
// async global->LDS DMA, 16B/lane; lds dest wave-uniform base + lane*16
static __device__ __forceinline__ void gl2lds(const unsigned char* g, unsigned char* l) {
    __builtin_amdgcn_global_load_lds(
        (const __attribute__((address_space(1))) void*)g,
        (__attribute__((address_space(3))) void*)l,
        16, 0, 0);
}

// ---------------------------------------------------------------- fused prep + CSR count
#define PA1 (256 * 448)
#define PA2 (448 * 448)
#define PA3 (448 * 32)
#define PXQ (NN * 64)   // x float4-quads
#define PTOT (PA1 + PA2 + PA3 + PXQ)
#define PBLK ((PTOT + 255) / 256)
#define CBLK ((ET + 255) / 256)

__global__ void gat_prepcnt_kernel(const float* __restrict__ W1, const float* __restrict__ W2,
                                   const float* __restrict__ W3, const float* __restrict__ x,
                                   unsigned char* __restrict__ Wt1, unsigned char* __restrict__ Wt2,
                                   unsigned char* __restrict__ Wt3, unsigned char* __restrict__ xb,
                                   const int* __restrict__ ei, int* __restrict__ cnt) {
    int b = blockIdx.x;
    if (b >= PBLK) {
        int i = (b - PBLK) * 256 + threadIdx.x;
        if (i < ET) {
            int dst = (i < EE) ? ei[EE + i] : (i - EE);
            atomicAdd(&cnt[dst], 1);
        }
        return;
    }
    int i = b * 256 + threadIdx.x;
    if (i < PA1) {
        int k = i / 448, n = i - k * 448;
        Wt1[(size_t)n * 256 + k] = f2fp8(W1[i]);
        return;
    }
    i -= PA1;
    if (i < PA2) {
        int k = i / 448, n = i - k * 448;
        Wt2[(size_t)n * 448 + k] = f2fp8(W2[i]);
        return;
    }
    i -= PA2;
    if (i < PA3) {
        int k = i / 32, n = i - k * 32;
        Wt3[(size_t)n * 448 + k] = f2fp8(W3[i]);
        return;
    }
    i -= PA3;
    if (i < PXQ) {
        float4 f = ((const float4*)x)[i];
        ((unsigned*)xb)[i] = pk4fp8(f.x, f.y, f.z, f.w);
    }
}

// ---------------------------------------------------------------- CSR scans (hierarchical, parallel) + fill
__global__ void gat_scan1_kernel(const int* __restrict__ cnt, int* __restrict__ tmp,
                                 int* __restrict__ part) {
    __shared__ int sm[256];
    int tid = threadIdx.x;
    int i = blockIdx.x * 256 + tid;
    int v = (i < NN) ? cnt[i] : 0;
    sm[tid] = v;
    __syncthreads();
    for (int o = 1; o < 256; o <<= 1) {
        int t = (tid >= o) ? sm[tid - o] : 0;
        __syncthreads();
        sm[tid] += t;
        __syncthreads();
    }
    if (i < NN) tmp[i] = sm[tid];
    if (tid == 255) part[blockIdx.x] = sm[255];
}

__global__ void gat_scan2_kernel(int* __restrict__ part) {
    __shared__ int sm[256];
    int tid = threadIdx.x;
    int v = (tid < NB_SCAN) ? part[tid] : 0;
    sm[tid] = v;
    __syncthreads();
    for (int o = 1; o < 256; o <<= 1) {
        int t = (tid >= o) ? sm[tid - o] : 0;
        __syncthreads();
        sm[tid] += t;
        __syncthreads();
    }
    part[tid] = sm[tid];
}

__global__ void gat_scan3_kernel(const int* __restrict__ tmp, const int* __restrict__ part,
                                 int* __restrict__ row_ptr) {
    int i = blockIdx.x * 256 + threadIdx.x;
    int off = (blockIdx.x > 0) ? part[blockIdx.x - 1] : 0;
    if (i < NN) row_ptr[i + 1] = tmp[i] + off;
    if (i == 0) row_ptr[0] = 0;
}

__global__ void gat_fill_kernel(const int* __restrict__ ei, const int* __restrict__ row_ptr,
                                int* __restrict__ fillc, int* __restrict__ colA) {
    int i = blockIdx.x * blockDim.x + threadIdx.x;
    if (i >= ET) return;
    int s, d;
    if (i < EE) { s = ei[i]; d = ei[EE + i]; }
    else        { s = d = i - EE; }
    int pos = row_ptr[d] + atomicAdd(&fillc[d], 1);
    colA[pos] = s;
}

// ---------------------------------------------------------------- GEMM core (fp8 A & W, fp8 MFMA, DMA staging, dbuf)
// C[M,N] = A[M,K] * W[K,N]; W pre-transposed fp8 Wt[N][K] (rows padded >= n0+64). A padded to NP rows.
// RF = 16-row frags/wave (BM = RF*64). GBK=64 (two K=32 MFMA steps per tile).
// DOA=1: fuse 64-ch alpha (head=blockIdx.y). DOA=2: 32-ch alpha. OM=0: C bf16; OM=1: C fp8.
#define GBN 64
#define GBK 64

template <int RF, int DOA, int OM>
__global__ __launch_bounds__(256) void gat_gemm_kernel(
    const unsigned char* __restrict__ A, const unsigned char* __restrict__ Wt,
    void* __restrict__ Cv,
    const float* __restrict__ Asrc, const float* __restrict__ Adst,
    float* __restrict__ as8, float* __restrict__ ad8,
    int M, int K, int N) {
    constexpr int GBM = RF * 64;
    __shared__ __align__(16) unsigned char As[2][GBM * GBK];
    __shared__ __align__(16) unsigned char Bs[2][GBN * GBK];
    int tid = threadIdx.x;
    int wave = tid >> 6, lane = tid & 63;
    int lrow = lane & 15, lq = lane >> 4;
    int m0 = blockIdx.x * GBM, n0 = blockIdx.y * GBN;
    int srow = lane >> 2, schunk = (lane & 3) * 16;     // 4 lanes per 64B row
    f32x4 acc[RF][4] = {};

    int KT = K / GBK;
    {
#pragma unroll
        for (int q = 0; q < RF; q++) {
            const unsigned char* gp = A + (size_t)(m0 + wave * RF * 16 + q * 16 + srow) * K + schunk;
            gl2lds(gp, &As[0][(wave * RF * 16 + q * 16) * GBK]);
        }
        const unsigned char* gb = Wt + (size_t)(n0 + wave * 16 + srow) * K + schunk;
        gl2lds(gb, &Bs[0][wave * 16 * GBK]);
    }
    for (int kt = 0; kt < KT; kt++) {
        __syncthreads();
        if (kt + 1 < KT) {
            int nb = (kt + 1) & 1, k0 = (kt + 1) * GBK;
#pragma unroll
            for (int q = 0; q < RF; q++) {
                const unsigned char* gp = A + (size_t)(m0 + wave * RF * 16 + q * 16 + srow) * K + k0 + schunk;
                gl2lds(gp, &As[nb][(wave * RF * 16 + q * 16) * GBK]);
            }
            const unsigned char* gb = Wt + (size_t)(n0 + wave * 16 + srow) * K + k0 + schunk;
            gl2lds(gb, &Bs[nb][wave * 16 * GBK]);
        }
        int b = kt & 1;
#pragma unroll
        for (int s = 0; s < 2; s++) {
            long af[RF];
#pragma unroll
            for (int rf = 0; rf < RF; rf++)
                af[rf] = *(const long*)&As[b][(wave * RF * 16 + rf * 16 + lrow) * GBK + s * 32 + lq * 8];
#pragma unroll
            for (int ng = 0; ng < 4; ng++) {
                long bf = *(const long*)&Bs[b][(ng * 16 + lrow) * GBK + s * 32 + lq * 8];
#pragma unroll
                for (int rf = 0; rf < RF; rf++)
                    acc[rf][ng] = __builtin_amdgcn_mfma_f32_16x16x32_fp8_fp8(af[rf], bf, acc[rf][ng], 0, 0, 0);
            }
        }
    }
    // epilogue: C/D layout col=lane&15 (within ng group), row=lq*4+r
#pragma unroll
    for (int rf = 0; rf < RF; rf++)
#pragma unroll
        for (int ng = 0; ng < 4; ng++)
#pragma unroll
            for (int r = 0; r < 4; r++) {
                int row = m0 + wave * RF * 16 + rf * 16 + lq * 4 + r;
                int colI = n0 + ng * 16 + lrow;
                if (row < M && colI < N) {
                    if constexpr (OM == 0)
                        ((__hip_bfloat16*)Cv)[(size_t)row * N + colI] = __float2bfloat16(acc[rf][ng][r]);
                    else
                        ((unsigned char*)Cv)[(size_t)row * N + colI] = f2fp8(acc[rf][ng][r]);
                }
            }
    if constexpr (DOA == 1) {
        int head = blockIdx.y;
        float as_l[4], ad_l[4];
#pragma unroll
        for (int ng = 0; ng < 4; ng++) {
            as_l[ng] = Asrc[head * 64 + ng * 16 + lrow];
            ad_l[ng] = Adst[head * 64 + ng * 16 + lrow];
        }
#pragma unroll
        for (int rf = 0; rf < RF; rf++)
#pragma unroll
            for (int r = 0; r < 4; r++) {
                float ps = 0.f, pd = 0.f;
#pragma unroll
                for (int ng = 0; ng < 4; ng++) {
                    ps += acc[rf][ng][r] * as_l[ng];
                    pd += acc[rf][ng][r] * ad_l[ng];
                }
#pragma unroll
                for (int o = 1; o < 16; o <<= 1) {
                    ps += __shfl_xor(ps, o);
                    pd += __shfl_xor(pd, o);
                }
                int row = m0 + wave * RF * 16 + rf * 16 + lq * 4 + r;
                if (lrow == 0 && row < M) {
                    as8[(size_t)row * 8 + head] = ps;
                    ad8[(size_t)row * 8 + head] = pd;
                }
            }
    } else if constexpr (DOA == 2) {
        float as_l[2], ad_l[2];
#pragma unroll
        for (int ng = 0; ng < 2; ng++) {
            as_l[ng] = Asrc[ng * 16 + lrow];
            ad_l[ng] = Adst[ng * 16 + lrow];
        }
#pragma unroll
        for (int rf = 0; rf < RF; rf++)
#pragma unroll
            for (int r = 0; r < 4; r++) {
                float ps = acc[rf][0][r] * as_l[0] + acc[rf][1][r] * as_l[1];
                float pd = acc[rf][0][r] * ad_l[0] + acc[rf][1][r] * ad_l[1];
#pragma unroll
                for (int o = 1; o < 16; o <<= 1) {
                    ps += __shfl_xor(ps, o);
                    pd += __shfl_xor(pd, o);
                }
                int row = m0 + wave * RF * 16 + rf * 16 + lq * 4 + r;
                if (lrow == 0 && row < M) {
                    as8[(size_t)row * 8] = ps;
                    ad8[(size_t)row * 8] = pd;
                }
            }
    }
}

// ---------------------------------------------------------------- Phase C: wave-per-dst, fp8 gather, fp8 act out
// lane l<56 owns head l>>3, channels 8l..8l+7 (8B/lane fp8 gather + 8B/lane fp8 store)
__global__ void gat_aggC7_kernel(const int* __restrict__ rp, const int* __restrict__ colA,
                                 const float* __restrict__ as8, const float* __restrict__ ad8,
                                 const unsigned char* __restrict__ h8,
                                 const float* __restrict__ bias,
                                 unsigned char* __restrict__ outp) {
    int d = blockIdx.x * 4 + (threadIdx.x >> 6);
    if (d >= NN) return;
    int lane = threadIdx.x & 63;
    if (lane >= 56) return;
    int hh = lane >> 3;
    float adh = ad8[(size_t)d * 8 + hh];
    int s0 = rp[d], s1 = rp[d + 1];
    float acc[8] = {0.f, 0.f, 0.f, 0.f, 0.f, 0.f, 0.f, 0.f};
    float den = 0.f;
    int j = s0;
    for (; j + 4 <= s1; j += 4) {
        int sA = colA[j], sB = colA[j + 1], sC = colA[j + 2], sD = colA[j + 3];
        float eA = as8[(size_t)sA * 8 + hh] + adh;
        float eB = as8[(size_t)sB * 8 + hh] + adh;
        float eC = as8[(size_t)sC * 8 + hh] + adh;
        float eD = as8[(size_t)sD * 8 + hh] + adh;
        uint2 hA = *(const uint2*)(h8 + (size_t)sA * 448 + lane * 8);
        uint2 hB = *(const uint2*)(h8 + (size_t)sB * 448 + lane * 8);
        uint2 hC = *(const uint2*)(h8 + (size_t)sC * 448 + lane * 8);
        uint2 hD = *(const uint2*)(h8 + (size_t)sD * 448 + lane * 8);
        eA = (eA > 0.f) ? eA : 0.2f * eA;
        eB = (eB > 0.f) ? eB : 0.2f * eB;
        eC = (eC > 0.f) ? eC : 0.2f * eC;
        eD = (eD > 0.f) ? eD : 0.2f * eD;
        float wA = __expf(eA), wB = __expf(eB);
        float wC = __expf(eC), wD = __expf(eD);
        den += (wA + wB) + (wC + wD);
        fp8acc4(hA.x, wA, &acc[0]); fp8acc4(hA.y, wA, &acc[4]);
        fp8acc4(hB.x, wB, &acc[0]); fp8acc4(hB.y, wB, &acc[4]);
        fp8acc4(hC.x, wC, &acc[0]); fp8acc4(hC.y, wC, &acc[4]);
        fp8acc4(hD.x, wD, &acc[0]); fp8acc4(hD.y, wD, &acc[4]);
    }
    for (; j < s1; j++) {
        int s = colA[j];
        float e = as8[(size_t)s * 8 + hh] + adh;
        e = (e > 0.f) ? e : 0.2f * e;
        float w = __expf(e);
        uint2 hv = *(const uint2*)(h8 + (size_t)s * 448 + lane * 8);
        den += w;
        fp8acc4(hv.x, w, &acc[0]);
        fp8acc4(hv.y, w, &acc[4]);
    }
    float inv = 1.f / (den + 1e-16f);
    const float4* bp = (const float4*)(bias + lane * 8);
    float4 bb0 = bp[0], bb1 = bp[1];
    float bv[8] = {bb0.x, bb0.y, bb0.z, bb0.w, bb1.x, bb1.y, bb1.z, bb1.w};
    float o[8];
#pragma unroll
    for (int k = 0; k < 8; k++) o[k] = fmaxf(acc[k] * inv + bv[k], 0.f);
    uint2 packed;
    packed.x = pk4fp8(o[0], o[1], o[2], o[3]);
    packed.y = pk4fp8(o[4], o[5], o[6], o[7]);
    *(uint2*)(outp + (size_t)d * 448 + lane * 8) = packed;
}

// ---------------------------------------------------------------- Phase C final: 2 dsts/wave, 32 ch (bf16 h3), log_softmax
__global__ void gat_aggCF_kernel(const int* __restrict__ rp, const int* __restrict__ colA,
                                 const float* __restrict__ as8, const float* __restrict__ ad8,
                                 const __hip_bfloat16* __restrict__ h,
                                 const float* __restrict__ bias,
                                 float* __restrict__ outp) {
    int wid = blockIdx.x * 4 + (threadIdx.x >> 6);
    int lane = threadIdx.x & 63;
    int half = lane >> 5, c = lane & 31;
    int dreal = wid * 2 + half;
    bool valid = dreal < NN;
    int d = valid ? dreal : (NN - 1);
    float adh = ad8[(size_t)d * 8];
    int s0 = rp[d], s1 = rp[d + 1];
    float acc = 0.f, den = 0.f;
    int j = s0;
    for (; j + 2 <= s1; j += 2) {
        int sA = colA[j], sB = colA[j + 1];
        float eA = as8[(size_t)sA * 8] + adh;
        float eB = as8[(size_t)sB * 8] + adh;
        float vA = bf2f(h[(size_t)sA * 32 + c]);
        float vB = bf2f(h[(size_t)sB * 32 + c]);
        eA = (eA > 0.f) ? eA : 0.2f * eA;
        eB = (eB > 0.f) ? eB : 0.2f * eB;
        float wA = __expf(eA), wB = __expf(eB);
        den += wA + wB;
        acc += wA * vA + wB * vB;
    }
    for (; j < s1; j++) {
        int s = colA[j];
        float e = as8[(size_t)s * 8] + adh;
        e = (e > 0.f) ? e : 0.2f * e;
        float w = __expf(e);
        den += w;
        acc += w * bf2f(h[(size_t)s * 32 + c]);
    }
    float o = acc / (den + 1e-16f) + bias[c];
    float t = o;
#pragma unroll
    for (int off = 16; off > 0; off >>= 1) t = fmaxf(t, __shfl_xor(t, off));
    float ex = __expf(o - t);
#pragma unroll
    for (int off = 16; off > 0; off >>= 1) ex += __shfl_xor(ex, off);
    float res = o - t - __logf(ex);
    if (valid) outp[(size_t)d * 32 + c] = res;
}

// ---------------------------------------------------------------- launch
extern "C" void kernel_launch(void* const* d_in, const int* in_sizes, int n_in,
                              void* d_out, int out_size, void* d_ws, size_t ws_size,
                              hipStream_t stream) {
    const float* x   = (const float*)d_in[0];
    const int*   ei  = (const int*)d_in[1];
    const float* W1  = (const float*)d_in[2];
    const float* a1s = (const float*)d_in[3];
    const float* a1d = (const float*)d_in[4];
    const float* b1  = (const float*)d_in[5];
    const float* W2  = (const float*)d_in[6];
    const float* a2s = (const float*)d_in[7];
    const float* a2d = (const float*)d_in[8];
    const float* b2  = (const float*)d_in[9];
    const float* W3  = (const float*)d_in[10];
    const float* a3s = (const float*)d_in[11];
    const float* a3d = (const float*)d_in[12];
    const float* b3  = (const float*)d_in[13];
    float* out = (float*)d_out;

    // workspace layout (~70 MB); all GEMM inputs fp8, padded to NP rows
    char* w = (char*)d_ws;
    unsigned char* hbuf8 = (unsigned char*)w;                  // NP*448 fp8 (22.5 MB); layer-3 reuses as bf16 NP*32
    __hip_bfloat16* hbuf3 = (__hip_bfloat16*)w;
    unsigned char* xb  = (unsigned char*)(w + (size_t)NP * 448);     // NP*256 fp8 (12.8 MB)
    unsigned char* act = xb + (size_t)NP * 256;                // NP*448 fp8 (22.5 MB)
    float* as8 = (float*)(act + (size_t)NP * 448);             // N*8 f32
    float* ad8 = as8 + (size_t)NN * 8;                         // N*8 f32
    int* cnt     = (int*)(ad8 + (size_t)NN * 8);               // N
    int* fillc   = cnt + NN;                                   // N
    int* row_ptr = fillc + NN;                                 // N+4 (padded)
    int* tmp     = row_ptr + (NN + 4);                         // N
    int* part    = tmp + NN;                                   // 256
    int* colA    = part + 256;                                 // ET
    char* pw = (char*)(colA + ET);
    pw = (char*)(((uintptr_t)pw + 15) & ~(uintptr_t)15);
    unsigned char* Wt1 = (unsigned char*)pw;                   // 448*256 fp8
    unsigned char* Wt2 = Wt1 + 448 * 256;                      // 448*448 fp8
    unsigned char* Wt3 = Wt2 + 448 * 448;                      // 64*448 fp8 (rows 32..63 poison, never stored)

    hipMemsetAsync(cnt, 0, 2 * (size_t)NN * sizeof(int), stream);  // cnt + fillc

    // fused prep (Wt x3 fp8 + x->fp8) + CSR count
    gat_prepcnt_kernel<<<PBLK + CBLK, 256, 0, stream>>>(W1, W2, W3, x, Wt1, Wt2, Wt3, xb, ei, cnt);
    gat_scan1_kernel<<<NB_SCAN, 256, 0, stream>>>(cnt, tmp, part);
    gat_scan2_kernel<<<1, 256, 0, stream>>>(part);
    gat_scan3_kernel<<<NB_SCAN, 256, 0, stream>>>(tmp, part, row_ptr);
    gat_fill_kernel<<<CBLK, 256, 0, stream>>>(ei, row_ptr, fillc, colA);

    dim3 gemmBlk(256);
    int mtiles = NP / 256;              // 196 (RF=4)
    int mtiles1 = NP / 64;              // 784 (RF=1, layer 3)
    int aggBlocks = (NN + 3) / 4;       // 12500

    // --- layer 1 (fp8 GEMM, alpha fused; h written fp8)
    gat_gemm_kernel<4, 1, 1><<<dim3(mtiles, 7), gemmBlk, 0, stream>>>(
        xb, Wt1, hbuf8, a1s, a1d, as8, ad8, NN, 256, 448);
    gat_aggC7_kernel<<<aggBlocks, 256, 0, stream>>>(row_ptr, colA, as8, ad8, hbuf8, b1, act);

    // --- layer 2
    gat_gemm_kernel<4, 1, 1><<<dim3(mtiles, 7), gemmBlk, 0, stream>>>(
        act, Wt2, hbuf8, a2s, a2d, as8, ad8, NN, 448, 448);
    gat_aggC7_kernel<<<aggBlocks, 256, 0, stream>>>(row_ptr, colA, as8, ad8, hbuf8, b2, act);

    // --- layer 3 (1 head, 32 ch, alpha fused, bf16 h3, RF=1, log_softmax, fp32 out)
    gat_gemm_kernel<1, 2, 0><<<dim3(mtiles1, 1), gemmBlk, 0, stream>>>(
        act, Wt3, hbuf3, a3s, a3d, as8, ad8, NN, 448, 32);
    int fBlocks = (NN + 7) / 8;  // 8 dsts per block (2 per wave)
    gat_aggCF_kernel<<<fBlocks, 256, 0, stream>>>(row_ptr, colA, as8, ad8, hbuf3, b3, out);
}